// Round 9
// baseline (4195.940 us; speedup 1.0000x reference)
//
#include <hip/hip_runtime.h>

#define Bn 32
#define Tn 512
#define Cn 8
#define Hn 256
#define Gn 1024            // 4*Hn
#define NTHR 128           // 2 waves: kg 0/1 (K-halves)
#define SLC  32            // slices per channel (each owns 8 h-indices, 32 gate rows)
#define NBLK (Cn*2*SLC)    // 512 workgroups: (channel, batch-half, slice)
#define K2n  (Hn/2)        // 128 k-pairs
#define EXU  (2*Cn*K2n*Bn) // 8-byte units per layer exchange array (double-buffered)
#define GP2  17            // gate-buffer pitch for 16 batches

typedef __attribute__((ext_vector_type(8))) __bf16 bf16x8;
typedef __attribute__((ext_vector_type(8))) short  short8;
typedef __attribute__((ext_vector_type(4))) float  f32x4;
typedef __attribute__((ext_vector_type(4))) unsigned uintx4;
typedef unsigned long long u64;

__device__ __forceinline__ unsigned bfr(float f) {            // fp32 -> bf16 bits, RNE
    unsigned u = __float_as_uint(f);
    return (u + 0x7fffu + ((u >> 16) & 1u)) >> 16;
}
__device__ __forceinline__ float sigmf(float v)  { return 1.0f / (1.0f + __expf(-v)); }
__device__ __forceinline__ float tanh_f(float v) { return 1.0f - 2.0f / (__expf(2.0f * v) + 1.0f); }

__device__ __forceinline__ f32x4 mf(short8 a, short8 b, f32x4 c) {
    return __builtin_amdgcn_mfma_f32_16x16x32_bf16(
        __builtin_bit_cast(bf16x8, a), __builtin_bit_cast(bf16x8, b), c, 0, 0, 0);
}

// split 8 consecutive fp32 into bf16 hi + bf16 lo fragments
__device__ __forceinline__ void splitw(const float* __restrict__ p, short8& hi, short8& lo) {
    short8 h, l;
#pragma unroll
    for (int j = 0; j < 8; ++j) {
        const float v = p[j];
        const unsigned hb = bfr(v);
        h[j] = (short)hb;
        l[j] = (short)bfr(v - __uint_as_float(hb << 16));
    }
    hi = h; lo = l;
}

// coherence-point (agent-scope, cache-bypassing) ops — all compiler-generated
__device__ __forceinline__ void ast(unsigned* p, unsigned v) {
    __hip_atomic_store(p, v, __ATOMIC_RELAXED, __HIP_MEMORY_SCOPE_AGENT);
}
__device__ __forceinline__ unsigned ald(const unsigned* p) {
    return __hip_atomic_load(p, __ATOMIC_RELAXED, __HIP_MEMORY_SCOPE_AGENT);
}
__device__ __forceinline__ void ast64(u64* p, u64 v) {
    __hip_atomic_store(p, v, __ATOMIC_RELAXED, __HIP_MEMORY_SCOPE_AGENT);
}
__device__ __forceinline__ u64 ald64(const u64* p) {
    return __hip_atomic_load(p, __ATOMIC_RELAXED, __HIP_MEMORY_SCOPE_AGENT);
}

__global__ void __launch_bounds__(NTHR, 2)
lstm_mfma(const float* __restrict__ x,
          const float* __restrict__ Wih1, const float* __restrict__ Whh1,
          const float* __restrict__ bih1, const float* __restrict__ bhh1,
          const float* __restrict__ Wih2, const float* __restrict__ Whh2,
          const float* __restrict__ bih2, const float* __restrict__ bhh2,
          const float* __restrict__ Wlin, const float* __restrict__ blin,
          float* __restrict__ out, void* __restrict__ wsv, int use_part) {
    __shared__ float g1buf[2 * 32 * GP2];   // [kg][32 gate rows][16 b] layer-1 K-partials
    __shared__ float g2buf[2 * 32 * GP2];   // layer-2 K-partials

    // exchange arrays: [2 buf][C][K2=128][B=32] of (hi-pair dword, lo-pair dword)
    u64* EX1 = (u64*)wsv;
    u64* EX2 = EX1 + EXU;
    unsigned* flags = (unsigned*)(EX2 + EXU);       // [C][2][SLC] monotone flags, 256B apart
    float* part = (float*)(flags + Cn * 2 * SLC * 64);  // [T][C][SLC][B] out partials

    const int tid  = threadIdx.x;
    const int wg   = blockIdx.x;
    const int c    = wg & 7;               // channel
    const int bh   = (wg >> 3) & 1;        // batch-half: independent pipeline
    const int s    = wg >> 4;              // slice: h-indices s*8 .. s*8+7
    const int lane = tid & 63;
    const int kg   = tid >> 6;             // K-group: k in [kg*128, kg*128+128)
    const int n    = lane & 15;
    const int quad = lane >> 4;
    const int bn   = bh * 16 + n;          // global batch of this lane's B-column

    // ---- permanent A-fragments: 3 weight matrices, 2 M-tiles, bf16 hi+lo, in VGPRs ----
    short8 w1h[2][4], w1l[2][4], w2h[2][4], w2l[2][4], w3h[2][4], w3l[2][4];
#pragma unroll
    for (int mt = 0; mt < 2; ++mt) {
        const int r = mt * 16 + n;                            // wg row (0..31)
        const size_t g = (size_t)((r >> 3) * Hn + s * 8 + (r & 7));
        const size_t base = (size_t)c * Gn * Hn + g * Hn + kg * 128 + quad * 8;
#pragma unroll
        for (int kk = 0; kk < 4; ++kk) {
            splitw(Whh1 + base + kk * 32, w1h[mt][kk], w1l[mt][kk]);
            splitw(Wih2 + base + kk * 32, w2h[mt][kk], w2l[mt][kk]);
            splitw(Whh2 + base + kk * 32, w3h[mt][kk], w3l[mt][kk]);
        }
    }

    // epilogue constants for the 8 accumulator rows (row = mt*16 + quad*4 + reg)
    float wi1_r[2][4], bs1_r[2][4], bs2_r[2][4];
#pragma unroll
    for (int mt = 0; mt < 2; ++mt)
#pragma unroll
        for (int reg = 0; reg < 4; ++reg) {
            const int r = mt * 16 + quad * 4 + reg;
            const int g = (r >> 3) * Hn + s * 8 + (r & 7);
            wi1_r[mt][reg] = Wih1[c * Gn + g];
            bs1_r[mt][reg] = bih1[c * Gn + g] + bhh1[c * Gn + g];
            bs2_r[mt][reg] = bih2[c * Gn + g] + bhh2[c * Gn + g];
        }

    // cell-update mapping: thread -> (jj = tid&7 h-idx within slice, bb = tid>>3 local batch)
    const int jj = tid & 7;
    const int bb = tid >> 3;               // 0..15
    const int gb = bh * 16 + bb;           // global batch
    const float wl = Wlin[c * Hn + s * 8 + jj];
    const float bl = blin[c];

    unsigned* myflags = flags + (c * 2 + bh) * SLC * 64;   // this pipeline's 32 flags

    float c1 = 0.0f, c2 = 0.0f;

    for (int t = 0; t <= Tn; ++t) {
        const bool doA = (t < Tn);      // layer-1 step t
        const bool doB = (t >= 1);      // layer-2 step t-1 (pipelined one behind)
        const int rd1 = (t + 1) & 1, wr1 = t & 1;        // h1 buffers
        const int rd2 = t & 1,       wr2 = (t + 1) & 1;  // h2 buffers

        const float xv = doA ? x[(bn * Tn + t) * Cn + c] : 0.0f;

        // ---- B-fragments via 8-byte coherence-point loads, [k2][b] layout ----
        const u64* E1 = EX1 + (size_t)(rd1 * Cn + c) * K2n * Bn;
        const u64* E2 = EX2 + (size_t)(rd2 * Cn + c) * K2n * Bn;
        short8 f2h[4], f2l[4], f1h[4], f1l[4];
#pragma unroll
        for (int kk = 0; kk < 4; ++kk) {
            uintx4 a2h, a2l, a1h, a1l;
#pragma unroll
            for (int j2 = 0; j2 < 4; ++j2) {
                const int k2 = kg * 64 + kk * 16 + quad * 4 + j2;
                const u64 v2 = ald64(E2 + k2 * Bn + bn);
                const u64 v1 = ald64(E1 + k2 * Bn + bn);
                a2h[j2] = (unsigned)v2; a2l[j2] = (unsigned)(v2 >> 32);
                a1h[j2] = (unsigned)v1; a1l[j2] = (unsigned)(v1 >> 32);
            }
            f2h[kk] = __builtin_bit_cast(short8, a2h);
            f2l[kk] = __builtin_bit_cast(short8, a2l);
            f1h[kk] = __builtin_bit_cast(short8, a1h);
            f1l[kk] = __builtin_bit_cast(short8, a1l);
        }

        f32x4 a1a[2] = {{0,0,0,0},{0,0,0,0}}, a1x[2] = {{0,0,0,0},{0,0,0,0}};
        f32x4 a2a[2] = {{0,0,0,0},{0,0,0,0}}, a2x[2] = {{0,0,0,0},{0,0,0,0}};
#pragma unroll
        for (int kk = 0; kk < 4; ++kk)
#pragma unroll
            for (int mt = 0; mt < 2; ++mt) {
                a2a[mt] = mf(w3h[mt][kk], f2h[kk], a2a[mt]);                       // Whh2.h2
                a2x[mt] = mf(w3l[mt][kk], f2h[kk], mf(w3h[mt][kk], f2l[kk], a2x[mt]));
                a1a[mt] = mf(w1h[mt][kk], f1h[kk], a1a[mt]);                       // Whh1.h1
                a1x[mt] = mf(w1l[mt][kk], f1h[kk], mf(w1h[mt][kk], f1l[kk], a1x[mt]));
                a2a[mt] = mf(w2h[mt][kk], f1h[kk], a2a[mt]);                       // Wih2.h1
                a2x[mt] = mf(w2l[mt][kk], f1h[kk], mf(w2h[mt][kk], f1l[kk], a2x[mt]));
            }

        // ---- write K-partial gates to LDS (C/D layout: col=lane&15, row=quad*4+reg) ----
#pragma unroll
        for (int mt = 0; mt < 2; ++mt)
#pragma unroll
            for (int reg = 0; reg < 4; ++reg) {
                const int r = mt * 16 + quad * 4 + reg;
                const int off = (kg * 32 + r) * GP2 + n;
                float e1 = a1a[mt][reg] + a1x[mt][reg];
                float e2 = a2a[mt][reg] + a2x[mt][reg];
                if (kg == 0) {                       // bias/x terms added once
                    e1 += xv * wi1_r[mt][reg] + bs1_r[mt][reg];
                    e2 += bs2_r[mt][reg];
                }
                g1buf[off] = e1;
                g2buf[off] = e2;
            }
        __syncthreads();

        // ---- layer-1 cell update, publish h1[t] as packed (hi,lo) 8-byte stores ----
        if (doA) {
            const float iv = sigmf (g1buf[jj * GP2 + bb]        + g1buf[(32 + jj) * GP2 + bb]);
            const float fv = sigmf (g1buf[(8 + jj) * GP2 + bb]  + g1buf[(40 + jj) * GP2 + bb]);
            const float gv = tanh_f(g1buf[(16 + jj) * GP2 + bb] + g1buf[(48 + jj) * GP2 + bb]);
            const float ov = sigmf (g1buf[(24 + jj) * GP2 + bb] + g1buf[(56 + jj) * GP2 + bb]);
            c1 = fv * c1 + iv * gv;
            const float h1v = ov * tanh_f(c1);
            const unsigned hb = bfr(h1v);
            const unsigned lb = bfr(h1v - __uint_as_float(hb << 16));
            const unsigned packed = (hb << 16) | lb;
            const unsigned nbp = (unsigned)__shfl_xor((int)packed, 1, 64);
            if ((jj & 1) == 0) {
                const unsigned hip = (packed >> 16) | (nbp & 0xffff0000u);
                const unsigned lop = (packed & 0xffffu) | (nbp << 16);
                const int k2 = s * 4 + (jj >> 1);
                ast64(EX1 + (size_t)(wr1 * Cn + c) * K2n * Bn + k2 * Bn + gb,
                      (u64)hip | ((u64)lop << 32));
            }
        }
        // ---- layer-2 cell update, publish h2[t-1], out partial ----
        if (doB) {
            const float iv = sigmf (g2buf[jj * GP2 + bb]        + g2buf[(32 + jj) * GP2 + bb]);
            const float fv = sigmf (g2buf[(8 + jj) * GP2 + bb]  + g2buf[(40 + jj) * GP2 + bb]);
            const float gv = tanh_f(g2buf[(16 + jj) * GP2 + bb] + g2buf[(48 + jj) * GP2 + bb]);
            const float ov = sigmf (g2buf[(24 + jj) * GP2 + bb] + g2buf[(56 + jj) * GP2 + bb]);
            c2 = fv * c2 + iv * gv;
            const float h2v = ov * tanh_f(c2);
            const unsigned hb = bfr(h2v);
            const unsigned lb = bfr(h2v - __uint_as_float(hb << 16));
            const unsigned packed = (hb << 16) | lb;
            const unsigned nbp = (unsigned)__shfl_xor((int)packed, 1, 64);
            if ((jj & 1) == 0) {
                const unsigned hip = (packed >> 16) | (nbp & 0xffff0000u);
                const unsigned lop = (packed & 0xffffu) | (nbp << 16);
                const int k2 = s * 4 + (jj >> 1);
                ast64(EX2 + (size_t)(wr2 * Cn + c) * K2n * Bn + k2 * Bn + gb,
                      (u64)hip | ((u64)lop << 32));
            }

            float pv = h2v * wl;                      // partial of out over this slice's 8 h
            pv += __shfl_xor(pv, 1, 64);
            pv += __shfl_xor(pv, 2, 64);
            pv += __shfl_xor(pv, 4, 64);
            if (jj == 0) {
                if (use_part) {
                    part[(((t - 1) * Cn + c) * SLC + s) * Bn + gb] = pv;
                } else {
                    atomicAdd(&out[(gb * Tn + (t - 1)) * Cn + c], pv + (s == 0 ? bl : 0.0f));
                }
            }
        }

        // ---- per-(channel, batch-half) barrier: 32 slice-flags, independent pipeline ----
        __syncthreads();
        if (tid == 0)
            ast(&myflags[s * 64], (unsigned)(t + 1));
        if (tid < 64) {
            bool mine;
            do {
                mine = (tid >= SLC) ||
                       (ald(&myflags[tid * 64]) >= (unsigned)(t + 1));
                if (__all((int)mine)) break;
                __builtin_amdgcn_s_sleep(1);
            } while (true);
        }
        __syncthreads();
    }
}

__global__ void reduce_out(const float* __restrict__ part, const float* __restrict__ blin,
                           float* __restrict__ out) {
    const int t = blockIdx.x;           // 512
    const int c = threadIdx.x >> 5;     // 8
    const int b = threadIdx.x & 31;     // 32
    float v = blin[c];
#pragma unroll
    for (int s = 0; s < SLC; ++s) v += part[((t * Cn + c) * SLC + s) * Bn + b];
    out[(b * Tn + t) * Cn + c] = v;
}

extern "C" void kernel_launch(void* const* d_in, const int* in_sizes, int n_in,
                              void* d_out, int out_size, void* d_ws, size_t ws_size,
                              hipStream_t stream) {
    const float* x    = (const float*)d_in[0];
    const float* Wih1 = (const float*)d_in[1];
    const float* Whh1 = (const float*)d_in[2];
    const float* bih1 = (const float*)d_in[3];
    const float* bhh1 = (const float*)d_in[4];
    const float* Wih2 = (const float*)d_in[5];
    const float* Whh2 = (const float*)d_in[6];
    const float* bih2 = (const float*)d_in[7];
    const float* bhh2 = (const float*)d_in[8];
    const float* Wlin = (const float*)d_in[9];
    const float* blin = (const float*)d_in[10];
    float* out = (float*)d_out;

    const size_t h_bytes    = (size_t)2 * EXU * sizeof(u64);                // 1 MiB
    const size_t flag_bytes = (size_t)Cn * 2 * SLC * 64 * sizeof(unsigned); // 128 KiB
    const size_t part_bytes = (size_t)Tn * Cn * SLC * Bn * sizeof(float);   // 16 MiB
    const int use_part = (ws_size >= h_bytes + flag_bytes + part_bytes) ? 1 : 0;

    hipMemsetAsync(d_ws, 0, h_bytes + flag_bytes, stream);   // zero h state + flags
    if (!use_part)
        hipMemsetAsync(d_out, 0, (size_t)out_size * sizeof(float), stream);

    lstm_mfma<<<NBLK, NTHR, 0, stream>>>(
        x, Wih1, Whh1, bih1, bhh1, Wih2, Whh2, bih2, bhh2, Wlin, blin, out, d_ws, use_part);

    if (use_part) {
        const float* part = (const float*)((const char*)d_ws + h_bytes + flag_bytes);
        reduce_out<<<Tn, Cn * Bn, 0, stream>>>(part, blin, out);
    }
}

// Round 10
// 2740.140 us; speedup vs baseline: 1.5313x; 1.5313x over previous
//
#include <hip/hip_runtime.h>

#define Bn 32
#define Tn 512
#define Cn 8
#define Hn 256
#define Gn 1024            // 4*Hn
#define NTHR 128           // 2 waves: kg 0/1 (K-halves)
#define SLC  32            // slices per channel (each owns 8 h-indices, 32 gate rows)
#define NBLK (Cn*2*SLC)    // 512 workgroups: (channel, batch-half, slice)
#define K2n  (Hn/2)        // 128 k-pairs
#define EXU  (2*Cn*K2n*Bn) // 8-byte units per layer exchange array (double-buffered)
#define GP2  18            // gate-buffer pitch: quad stride 72B = 8 banks -> 2-way (free)

typedef __attribute__((ext_vector_type(8))) __bf16 bf16x8;
typedef __attribute__((ext_vector_type(8))) short  short8;
typedef __attribute__((ext_vector_type(4))) float  f32x4;
typedef __attribute__((ext_vector_type(4))) unsigned uintx4;
typedef unsigned long long u64;

__device__ __forceinline__ unsigned bfr(float f) {            // fp32 -> bf16 bits, RNE
    unsigned u = __float_as_uint(f);
    return (u + 0x7fffu + ((u >> 16) & 1u)) >> 16;
}
__device__ __forceinline__ float sigmf(float v)  { return 1.0f / (1.0f + __expf(-v)); }
__device__ __forceinline__ float tanh_f(float v) { return 1.0f - 2.0f / (__expf(2.0f * v) + 1.0f); }

__device__ __forceinline__ f32x4 mf(short8 a, short8 b, f32x4 c) {
    return __builtin_amdgcn_mfma_f32_16x16x32_bf16(
        __builtin_bit_cast(bf16x8, a), __builtin_bit_cast(bf16x8, b), c, 0, 0, 0);
}

// split 8 consecutive fp32 into bf16 hi + bf16 lo fragments
__device__ __forceinline__ void splitw(const float* __restrict__ p, short8& hi, short8& lo) {
    short8 h, l;
#pragma unroll
    for (int j = 0; j < 8; ++j) {
        const float v = p[j];
        const unsigned hb = bfr(v);
        h[j] = (short)hb;
        l[j] = (short)bfr(v - __uint_as_float(hb << 16));
    }
    hi = h; lo = l;
}

// coherence-point (agent-scope, cache-bypassing) ops — all compiler-generated
__device__ __forceinline__ void ast(unsigned* p, unsigned v) {
    __hip_atomic_store(p, v, __ATOMIC_RELAXED, __HIP_MEMORY_SCOPE_AGENT);
}
__device__ __forceinline__ unsigned ald(const unsigned* p) {
    return __hip_atomic_load(p, __ATOMIC_RELAXED, __HIP_MEMORY_SCOPE_AGENT);
}
__device__ __forceinline__ void ast64(u64* p, u64 v) {
    __hip_atomic_store(p, v, __ATOMIC_RELAXED, __HIP_MEMORY_SCOPE_AGENT);
}
__device__ __forceinline__ u64 ald64(const u64* p) {
    return __hip_atomic_load(p, __ATOMIC_RELAXED, __HIP_MEMORY_SCOPE_AGENT);
}

__global__ void __launch_bounds__(NTHR, 1)
lstm_mfma(const float* __restrict__ x,
          const float* __restrict__ Wih1, const float* __restrict__ Whh1,
          const float* __restrict__ bih1, const float* __restrict__ bhh1,
          const float* __restrict__ Wih2, const float* __restrict__ Whh2,
          const float* __restrict__ bih2, const float* __restrict__ bhh2,
          const float* __restrict__ Wlin, const float* __restrict__ blin,
          float* __restrict__ out, void* __restrict__ wsv, int use_part) {
    __shared__ float g1buf[2 * 32 * GP2];   // [kg][32 gate rows][16 b] layer-1 K-partials
    __shared__ float g2buf[2 * 32 * GP2];   // layer-2 K-partials

    // exchange arrays: [2 buf][C][K2=128][B=32] of (hi-pair dword, lo-pair dword)
    u64* EX1 = (u64*)wsv;
    u64* EX2 = EX1 + EXU;
    unsigned* flags = (unsigned*)(EX2 + EXU);       // [C][2][SLC] monotone flags, 256B apart
    float* part = (float*)(flags + Cn * 2 * SLC * 64);  // [T][C][SLC][B] out partials

    const int tid  = threadIdx.x;
    const int wg   = blockIdx.x;
    const int c    = wg & 7;               // channel
    const int bh   = (wg >> 3) & 1;        // batch-half: independent pipeline
    const int s    = wg >> 4;              // slice: h-indices s*8 .. s*8+7
    const int lane = tid & 63;
    const int kg   = tid >> 6;             // K-group: k in [kg*128, kg*128+128)
    const int n    = lane & 15;
    const int quad = lane >> 4;
    const int bn   = bh * 16 + n;          // global batch of this lane's B-column

    // ---- permanent A-fragments: 3 weight matrices, 2 M-tiles, bf16 hi+lo, in VGPRs ----
    short8 w1h[2][4], w1l[2][4], w2h[2][4], w2l[2][4], w3h[2][4], w3l[2][4];
#pragma unroll
    for (int mt = 0; mt < 2; ++mt) {
        const int r = mt * 16 + n;                            // wg row (0..31)
        const size_t g = (size_t)((r >> 3) * Hn + s * 8 + (r & 7));
        const size_t base = (size_t)c * Gn * Hn + g * Hn + kg * 128 + quad * 8;
#pragma unroll
        for (int kk = 0; kk < 4; ++kk) {
            splitw(Whh1 + base + kk * 32, w1h[mt][kk], w1l[mt][kk]);
            splitw(Wih2 + base + kk * 32, w2h[mt][kk], w2l[mt][kk]);
            splitw(Whh2 + base + kk * 32, w3h[mt][kk], w3l[mt][kk]);
        }
    }

    // epilogue constants for the 8 accumulator rows (row = mt*16 + quad*4 + reg)
    float wi1_r[2][4], bs1_r[2][4], bs2_r[2][4];
#pragma unroll
    for (int mt = 0; mt < 2; ++mt)
#pragma unroll
        for (int reg = 0; reg < 4; ++reg) {
            const int r = mt * 16 + quad * 4 + reg;
            const int g = (r >> 3) * Hn + s * 8 + (r & 7);
            wi1_r[mt][reg] = Wih1[c * Gn + g];
            bs1_r[mt][reg] = bih1[c * Gn + g] + bhh1[c * Gn + g];
            bs2_r[mt][reg] = bih2[c * Gn + g] + bhh2[c * Gn + g];
        }

    // cell-update mapping: thread -> (jj = tid&7 h-idx within slice, bb = tid>>3 local batch)
    const int jj = tid & 7;
    const int bb = tid >> 3;               // 0..15
    const int gb = bh * 16 + bb;           // global batch
    const float wl = Wlin[c * Hn + s * 8 + jj];
    const float bl = blin[c];

    unsigned* myflags = flags + (c * 2 + bh) * SLC * 64;   // this pipeline's 32 flags

    float c1 = 0.0f, c2 = 0.0f;

    for (int t = 0; t <= Tn; ++t) {
        const bool doA = (t < Tn);      // layer-1 step t
        const bool doB = (t >= 1);      // layer-2 step t-1 (pipelined one behind)
        const int rd1 = (t + 1) & 1, wr1 = t & 1;        // h1 buffers
        const int rd2 = t & 1,       wr2 = (t + 1) & 1;  // h2 buffers

        const float xv = doA ? x[(bn * Tn + t) * Cn + c] : 0.0f;

        // ---- B-fragments via 8-byte coherence-point loads, [k2][b] layout ----
        const u64* E1 = EX1 + (size_t)(rd1 * Cn + c) * K2n * Bn;
        const u64* E2 = EX2 + (size_t)(rd2 * Cn + c) * K2n * Bn;
        short8 f2h[4], f2l[4], f1h[4], f1l[4];
#pragma unroll
        for (int kk = 0; kk < 4; ++kk) {
            uintx4 a2h, a2l, a1h, a1l;
#pragma unroll
            for (int j2 = 0; j2 < 4; ++j2) {
                const int k2 = kg * 64 + kk * 16 + quad * 4 + j2;
                const u64 v2 = ald64(E2 + k2 * Bn + bn);
                const u64 v1 = ald64(E1 + k2 * Bn + bn);
                a2h[j2] = (unsigned)v2; a2l[j2] = (unsigned)(v2 >> 32);
                a1h[j2] = (unsigned)v1; a1l[j2] = (unsigned)(v1 >> 32);
            }
            f2h[kk] = __builtin_bit_cast(short8, a2h);
            f2l[kk] = __builtin_bit_cast(short8, a2l);
            f1h[kk] = __builtin_bit_cast(short8, a1h);
            f1l[kk] = __builtin_bit_cast(short8, a1l);
        }

        f32x4 a1a[2] = {{0,0,0,0},{0,0,0,0}}, a1x[2] = {{0,0,0,0},{0,0,0,0}};
        f32x4 a2a[2] = {{0,0,0,0},{0,0,0,0}}, a2x[2] = {{0,0,0,0},{0,0,0,0}};
#pragma unroll
        for (int kk = 0; kk < 4; ++kk)
#pragma unroll
            for (int mt = 0; mt < 2; ++mt) {
                a2a[mt] = mf(w3h[mt][kk], f2h[kk], a2a[mt]);                       // Whh2.h2
                a2x[mt] = mf(w3l[mt][kk], f2h[kk], mf(w3h[mt][kk], f2l[kk], a2x[mt]));
                a1a[mt] = mf(w1h[mt][kk], f1h[kk], a1a[mt]);                       // Whh1.h1
                a1x[mt] = mf(w1l[mt][kk], f1h[kk], mf(w1h[mt][kk], f1l[kk], a1x[mt]));
                a2a[mt] = mf(w2h[mt][kk], f1h[kk], a2a[mt]);                       // Wih2.h1
                a2x[mt] = mf(w2l[mt][kk], f1h[kk], mf(w2h[mt][kk], f1l[kk], a2x[mt]));
            }

        // ---- write K-partial gates to LDS (C/D layout: col=lane&15, row=quad*4+reg) ----
#pragma unroll
        for (int mt = 0; mt < 2; ++mt)
#pragma unroll
            for (int reg = 0; reg < 4; ++reg) {
                const int r = mt * 16 + quad * 4 + reg;
                const int off = (kg * 32 + r) * GP2 + n;
                float e1 = a1a[mt][reg] + a1x[mt][reg];
                float e2 = a2a[mt][reg] + a2x[mt][reg];
                if (kg == 0) {                       // bias/x terms added once
                    e1 += xv * wi1_r[mt][reg] + bs1_r[mt][reg];
                    e2 += bs2_r[mt][reg];
                }
                g1buf[off] = e1;
                g2buf[off] = e2;
            }
        __syncthreads();

        // ---- layer-1 cell update, publish h1[t] as packed (hi,lo) 8-byte stores ----
        if (doA) {
            const float iv = sigmf (g1buf[jj * GP2 + bb]        + g1buf[(32 + jj) * GP2 + bb]);
            const float fv = sigmf (g1buf[(8 + jj) * GP2 + bb]  + g1buf[(40 + jj) * GP2 + bb]);
            const float gv = tanh_f(g1buf[(16 + jj) * GP2 + bb] + g1buf[(48 + jj) * GP2 + bb]);
            const float ov = sigmf (g1buf[(24 + jj) * GP2 + bb] + g1buf[(56 + jj) * GP2 + bb]);
            c1 = fv * c1 + iv * gv;
            const float h1v = ov * tanh_f(c1);
            const unsigned hb = bfr(h1v);
            const unsigned lb = bfr(h1v - __uint_as_float(hb << 16));
            const unsigned packed = (hb << 16) | lb;
            const unsigned nbp = (unsigned)__shfl_xor((int)packed, 1, 64);
            if ((jj & 1) == 0) {
                const unsigned hip = (packed >> 16) | (nbp & 0xffff0000u);
                const unsigned lop = (packed & 0xffffu) | (nbp << 16);
                const int k2 = s * 4 + (jj >> 1);
                ast64(EX1 + (size_t)(wr1 * Cn + c) * K2n * Bn + k2 * Bn + gb,
                      (u64)hip | ((u64)lop << 32));
            }
        }
        // ---- layer-2 cell update, publish h2[t-1], out partial ----
        if (doB) {
            const float iv = sigmf (g2buf[jj * GP2 + bb]        + g2buf[(32 + jj) * GP2 + bb]);
            const float fv = sigmf (g2buf[(8 + jj) * GP2 + bb]  + g2buf[(40 + jj) * GP2 + bb]);
            const float gv = tanh_f(g2buf[(16 + jj) * GP2 + bb] + g2buf[(48 + jj) * GP2 + bb]);
            const float ov = sigmf (g2buf[(24 + jj) * GP2 + bb] + g2buf[(56 + jj) * GP2 + bb]);
            c2 = fv * c2 + iv * gv;
            const float h2v = ov * tanh_f(c2);
            const unsigned hb = bfr(h2v);
            const unsigned lb = bfr(h2v - __uint_as_float(hb << 16));
            const unsigned packed = (hb << 16) | lb;
            const unsigned nbp = (unsigned)__shfl_xor((int)packed, 1, 64);
            if ((jj & 1) == 0) {
                const unsigned hip = (packed >> 16) | (nbp & 0xffff0000u);
                const unsigned lop = (packed & 0xffffu) | (nbp << 16);
                const int k2 = s * 4 + (jj >> 1);
                ast64(EX2 + (size_t)(wr2 * Cn + c) * K2n * Bn + k2 * Bn + gb,
                      (u64)hip | ((u64)lop << 32));
            }

            float pv = h2v * wl;                      // partial of out over this slice's 8 h
            pv += __shfl_xor(pv, 1, 64);
            pv += __shfl_xor(pv, 2, 64);
            pv += __shfl_xor(pv, 4, 64);
            if (jj == 0) {
                if (use_part) {
                    part[(((t - 1) * Cn + c) * SLC + s) * Bn + gb] = pv;
                } else {
                    atomicAdd(&out[(gb * Tn + (t - 1)) * Cn + c], pv + (s == 0 ? bl : 0.0f));
                }
            }
        }

        // ---- per-(channel, batch-half) barrier: 32 slice-flags, independent pipeline ----
        __syncthreads();
        if (tid == 0)
            ast(&myflags[s * 64], (unsigned)(t + 1));
        if (tid < 64) {
            bool mine;
            do {
                mine = (tid >= SLC) ||
                       (ald(&myflags[tid * 64]) >= (unsigned)(t + 1));
                if (__all((int)mine)) break;
                __builtin_amdgcn_s_sleep(1);
            } while (true);
        }
        __syncthreads();
    }
}

__global__ void reduce_out(const float* __restrict__ part, const float* __restrict__ blin,
                           float* __restrict__ out) {
    const int t = blockIdx.x;           // 512
    const int c = threadIdx.x >> 5;     // 8
    const int b = threadIdx.x & 31;     // 32
    float v = blin[c];
#pragma unroll
    for (int s = 0; s < SLC; ++s) v += part[((t * Cn + c) * SLC + s) * Bn + b];
    out[(b * Tn + t) * Cn + c] = v;
}

extern "C" void kernel_launch(void* const* d_in, const int* in_sizes, int n_in,
                              void* d_out, int out_size, void* d_ws, size_t ws_size,
                              hipStream_t stream) {
    const float* x    = (const float*)d_in[0];
    const float* Wih1 = (const float*)d_in[1];
    const float* Whh1 = (const float*)d_in[2];
    const float* bih1 = (const float*)d_in[3];
    const float* bhh1 = (const float*)d_in[4];
    const float* Wih2 = (const float*)d_in[5];
    const float* Whh2 = (const float*)d_in[6];
    const float* bih2 = (const float*)d_in[7];
    const float* bhh2 = (const float*)d_in[8];
    const float* Wlin = (const float*)d_in[9];
    const float* blin = (const float*)d_in[10];
    float* out = (float*)d_out;

    const size_t h_bytes    = (size_t)2 * EXU * sizeof(u64);                // 1 MiB
    const size_t flag_bytes = (size_t)Cn * 2 * SLC * 64 * sizeof(unsigned); // 128 KiB
    const size_t part_bytes = (size_t)Tn * Cn * SLC * Bn * sizeof(float);   // 16 MiB
    const int use_part = (ws_size >= h_bytes + flag_bytes + part_bytes) ? 1 : 0;

    hipMemsetAsync(d_ws, 0, h_bytes + flag_bytes, stream);   // zero h state + flags
    if (!use_part)
        hipMemsetAsync(d_out, 0, (size_t)out_size * sizeof(float), stream);

    lstm_mfma<<<NBLK, NTHR, 0, stream>>>(
        x, Wih1, Whh1, bih1, bhh1, Wih2, Whh2, bih2, bhh2, Wlin, blin, out, d_ws, use_part);

    if (use_part) {
        const float* part = (const float*)((const char*)d_ws + h_bytes + flag_bytes);
        reduce_out<<<Tn, Cn * Bn, 0, stream>>>(part, blin, out);
    }
}

// Round 11
// 2704.480 us; speedup vs baseline: 1.5515x; 1.0132x over previous
//
#include <hip/hip_runtime.h>

#define Bn 32
#define Tn 512
#define Cn 8
#define Hn 256
#define Gn 1024            // 4*Hn
#define NTHR 128           // 2 waves: kg 0/1 (K-halves)
#define SLC  32            // slices per channel (each owns 8 h-indices, 32 gate rows)
#define NBLK (Cn*2*SLC)    // 512 workgroups: (channel, batch-half, slice)
#define K2n  (Hn/2)        // 128 k-pairs
#define EXU  (2*Cn*K2n*Bn) // 8-byte units per layer exchange array (double-buffered)
#define GP2  18            // gate-buffer pitch: quad stride 72B = 8 banks -> 2-way (free)

typedef __attribute__((ext_vector_type(8))) __bf16 bf16x8;
typedef __attribute__((ext_vector_type(8))) short  short8;
typedef __attribute__((ext_vector_type(4))) float  f32x4;
typedef __attribute__((ext_vector_type(4))) unsigned uintx4;
typedef unsigned long long u64;

__device__ __forceinline__ unsigned bfr(float f) {            // fp32 -> bf16 bits, RNE
    unsigned u = __float_as_uint(f);
    return (u + 0x7fffu + ((u >> 16) & 1u)) >> 16;
}
__device__ __forceinline__ float sigmf(float v)  { return 1.0f / (1.0f + __expf(-v)); }
__device__ __forceinline__ float tanh_f(float v) { return 1.0f - 2.0f / (__expf(2.0f * v) + 1.0f); }

__device__ __forceinline__ f32x4 mf(short8 a, short8 b, f32x4 c) {
    return __builtin_amdgcn_mfma_f32_16x16x32_bf16(
        __builtin_bit_cast(bf16x8, a), __builtin_bit_cast(bf16x8, b), c, 0, 0, 0);
}

// split 8 consecutive fp32 into bf16 hi + bf16 lo fragments
__device__ __forceinline__ void splitw(const float* __restrict__ p, short8& hi, short8& lo) {
    short8 h, l;
#pragma unroll
    for (int j = 0; j < 8; ++j) {
        const float v = p[j];
        const unsigned hb = bfr(v);
        h[j] = (short)hb;
        l[j] = (short)bfr(v - __uint_as_float(hb << 16));
    }
    hi = h; lo = l;
}

// coherence-point (agent-scope, cache-bypassing) ops — all compiler-generated
__device__ __forceinline__ void ast(unsigned* p, unsigned v) {
    __hip_atomic_store(p, v, __ATOMIC_RELAXED, __HIP_MEMORY_SCOPE_AGENT);
}
__device__ __forceinline__ unsigned ald(const unsigned* p) {
    return __hip_atomic_load(p, __ATOMIC_RELAXED, __HIP_MEMORY_SCOPE_AGENT);
}
__device__ __forceinline__ void ast64(u64* p, u64 v) {
    __hip_atomic_store(p, v, __ATOMIC_RELAXED, __HIP_MEMORY_SCOPE_AGENT);
}
__device__ __forceinline__ u64 ald64(const u64* p) {
    return __hip_atomic_load(p, __ATOMIC_RELAXED, __HIP_MEMORY_SCOPE_AGENT);
}

__global__ void __launch_bounds__(NTHR, 1)
lstm_mfma(const float* __restrict__ x,
          const float* __restrict__ Wih1, const float* __restrict__ Whh1,
          const float* __restrict__ bih1, const float* __restrict__ bhh1,
          const float* __restrict__ Wih2, const float* __restrict__ Whh2,
          const float* __restrict__ bih2, const float* __restrict__ bhh2,
          const float* __restrict__ Wlin, const float* __restrict__ blin,
          float* __restrict__ out, void* __restrict__ wsv, int use_part) {
    __shared__ float g1buf[2 * 32 * GP2];   // [kg][32 gate rows][16 b] layer-1 K-partials
    __shared__ float g2buf[2 * 32 * GP2];   // layer-2 K-partials

    // exchange arrays: [2 buf][C][K2=128][B=32] of (hi-pair dword, lo-pair dword)
    u64* EX1 = (u64*)wsv;
    u64* EX2 = EX1 + EXU;
    unsigned* flags = (unsigned*)(EX2 + EXU);       // [C][2][SLC] monotone flags, 256B apart
    float* part = (float*)(flags + Cn * 2 * SLC * 64);  // [T][C][SLC][B] out partials

    const int tid  = threadIdx.x;
    const int wg   = blockIdx.x;
    const int c    = wg & 7;               // channel
    // bh from the HIGH bit: blocks i and i+256 share a CU under round-robin dispatch;
    // this makes the CU's two wgs belong to DIFFERENT pipelines (phase-independent),
    // so one pipeline's compute hides the other's barrier latency. r10's (wg>>3)&1
    // put both co-resident wgs in the SAME pipeline -> phase-locked, no overlap.
    const int bh   = (wg >> 8) & 1;        // batch-half: independent pipeline
    const int s    = (wg >> 3) & 31;       // slice: h-indices s*8 .. s*8+7
    const int lane = tid & 63;
    const int kg   = tid >> 6;             // K-group: k in [kg*128, kg*128+128)
    const int n    = lane & 15;
    const int quad = lane >> 4;
    const int bn   = bh * 16 + n;          // global batch of this lane's B-column

    // ---- permanent A-fragments: 3 weight matrices, 2 M-tiles, bf16 hi+lo, in VGPRs ----
    short8 w1h[2][4], w1l[2][4], w2h[2][4], w2l[2][4], w3h[2][4], w3l[2][4];
#pragma unroll
    for (int mt = 0; mt < 2; ++mt) {
        const int r = mt * 16 + n;                            // wg row (0..31)
        const size_t g = (size_t)((r >> 3) * Hn + s * 8 + (r & 7));
        const size_t base = (size_t)c * Gn * Hn + g * Hn + kg * 128 + quad * 8;
#pragma unroll
        for (int kk = 0; kk < 4; ++kk) {
            splitw(Whh1 + base + kk * 32, w1h[mt][kk], w1l[mt][kk]);
            splitw(Wih2 + base + kk * 32, w2h[mt][kk], w2l[mt][kk]);
            splitw(Whh2 + base + kk * 32, w3h[mt][kk], w3l[mt][kk]);
        }
    }

    // epilogue constants for the 8 accumulator rows (row = mt*16 + quad*4 + reg)
    float wi1_r[2][4], bs1_r[2][4], bs2_r[2][4];
#pragma unroll
    for (int mt = 0; mt < 2; ++mt)
#pragma unroll
        for (int reg = 0; reg < 4; ++reg) {
            const int r = mt * 16 + quad * 4 + reg;
            const int g = (r >> 3) * Hn + s * 8 + (r & 7);
            wi1_r[mt][reg] = Wih1[c * Gn + g];
            bs1_r[mt][reg] = bih1[c * Gn + g] + bhh1[c * Gn + g];
            bs2_r[mt][reg] = bih2[c * Gn + g] + bhh2[c * Gn + g];
        }

    // cell-update mapping: thread -> (jj = tid&7 h-idx within slice, bb = tid>>3 local batch)
    const int jj = tid & 7;
    const int bb = tid >> 3;               // 0..15
    const int gb = bh * 16 + bb;           // global batch
    const float wl = Wlin[c * Hn + s * 8 + jj];
    const float bl = blin[c];

    unsigned* myflags = flags + (c * 2 + bh) * SLC * 64;   // this pipeline's 32 flags

    float c1 = 0.0f, c2 = 0.0f;

    for (int t = 0; t <= Tn; ++t) {
        const bool doA = (t < Tn);      // layer-1 step t
        const bool doB = (t >= 1);      // layer-2 step t-1 (pipelined one behind)
        const int rd1 = (t + 1) & 1, wr1 = t & 1;        // h1 buffers
        const int rd2 = t & 1,       wr2 = (t + 1) & 1;  // h2 buffers

        const float xv = doA ? x[(bn * Tn + t) * Cn + c] : 0.0f;

        // ---- B-fragments via 8-byte coherence-point loads, [k2][b] layout ----
        const u64* E1 = EX1 + (size_t)(rd1 * Cn + c) * K2n * Bn;
        const u64* E2 = EX2 + (size_t)(rd2 * Cn + c) * K2n * Bn;
        short8 f2h[4], f2l[4], f1h[4], f1l[4];
#pragma unroll
        for (int kk = 0; kk < 4; ++kk) {
            uintx4 a2h, a2l, a1h, a1l;
#pragma unroll
            for (int j2 = 0; j2 < 4; ++j2) {
                const int k2 = kg * 64 + kk * 16 + quad * 4 + j2;
                const u64 v2 = ald64(E2 + k2 * Bn + bn);
                const u64 v1 = ald64(E1 + k2 * Bn + bn);
                a2h[j2] = (unsigned)v2; a2l[j2] = (unsigned)(v2 >> 32);
                a1h[j2] = (unsigned)v1; a1l[j2] = (unsigned)(v1 >> 32);
            }
            f2h[kk] = __builtin_bit_cast(short8, a2h);
            f2l[kk] = __builtin_bit_cast(short8, a2l);
            f1h[kk] = __builtin_bit_cast(short8, a1h);
            f1l[kk] = __builtin_bit_cast(short8, a1l);
        }

        f32x4 a1a[2] = {{0,0,0,0},{0,0,0,0}}, a1x[2] = {{0,0,0,0},{0,0,0,0}};
        f32x4 a2a[2] = {{0,0,0,0},{0,0,0,0}}, a2x[2] = {{0,0,0,0},{0,0,0,0}};
#pragma unroll
        for (int kk = 0; kk < 4; ++kk)
#pragma unroll
            for (int mt = 0; mt < 2; ++mt) {
                a2a[mt] = mf(w3h[mt][kk], f2h[kk], a2a[mt]);                       // Whh2.h2
                a2x[mt] = mf(w3l[mt][kk], f2h[kk], mf(w3h[mt][kk], f2l[kk], a2x[mt]));
                a1a[mt] = mf(w1h[mt][kk], f1h[kk], a1a[mt]);                       // Whh1.h1
                a1x[mt] = mf(w1l[mt][kk], f1h[kk], mf(w1h[mt][kk], f1l[kk], a1x[mt]));
                a2a[mt] = mf(w2h[mt][kk], f1h[kk], a2a[mt]);                       // Wih2.h1
                a2x[mt] = mf(w2l[mt][kk], f1h[kk], mf(w2h[mt][kk], f1l[kk], a2x[mt]));
            }

        // ---- write K-partial gates to LDS (C/D layout: col=lane&15, row=quad*4+reg) ----
#pragma unroll
        for (int mt = 0; mt < 2; ++mt)
#pragma unroll
            for (int reg = 0; reg < 4; ++reg) {
                const int r = mt * 16 + quad * 4 + reg;
                const int off = (kg * 32 + r) * GP2 + n;
                float e1 = a1a[mt][reg] + a1x[mt][reg];
                float e2 = a2a[mt][reg] + a2x[mt][reg];
                if (kg == 0) {                       // bias/x terms added once
                    e1 += xv * wi1_r[mt][reg] + bs1_r[mt][reg];
                    e2 += bs2_r[mt][reg];
                }
                g1buf[off] = e1;
                g2buf[off] = e2;
            }
        __syncthreads();

        // ---- layer-1 cell update, publish h1[t] as packed (hi,lo) 8-byte stores ----
        if (doA) {
            const float iv = sigmf (g1buf[jj * GP2 + bb]        + g1buf[(32 + jj) * GP2 + bb]);
            const float fv = sigmf (g1buf[(8 + jj) * GP2 + bb]  + g1buf[(40 + jj) * GP2 + bb]);
            const float gv = tanh_f(g1buf[(16 + jj) * GP2 + bb] + g1buf[(48 + jj) * GP2 + bb]);
            const float ov = sigmf (g1buf[(24 + jj) * GP2 + bb] + g1buf[(56 + jj) * GP2 + bb]);
            c1 = fv * c1 + iv * gv;
            const float h1v = ov * tanh_f(c1);
            const unsigned hb = bfr(h1v);
            const unsigned lb = bfr(h1v - __uint_as_float(hb << 16));
            const unsigned packed = (hb << 16) | lb;
            const unsigned nbp = (unsigned)__shfl_xor((int)packed, 1, 64);
            if ((jj & 1) == 0) {
                const unsigned hip = (packed >> 16) | (nbp & 0xffff0000u);
                const unsigned lop = (packed & 0xffffu) | (nbp << 16);
                const int k2 = s * 4 + (jj >> 1);
                ast64(EX1 + (size_t)(wr1 * Cn + c) * K2n * Bn + k2 * Bn + gb,
                      (u64)hip | ((u64)lop << 32));
            }
        }
        // ---- layer-2 cell update, publish h2[t-1], out partial ----
        if (doB) {
            const float iv = sigmf (g2buf[jj * GP2 + bb]        + g2buf[(32 + jj) * GP2 + bb]);
            const float fv = sigmf (g2buf[(8 + jj) * GP2 + bb]  + g2buf[(40 + jj) * GP2 + bb]);
            const float gv = tanh_f(g2buf[(16 + jj) * GP2 + bb] + g2buf[(48 + jj) * GP2 + bb]);
            const float ov = sigmf (g2buf[(24 + jj) * GP2 + bb] + g2buf[(56 + jj) * GP2 + bb]);
            c2 = fv * c2 + iv * gv;
            const float h2v = ov * tanh_f(c2);
            const unsigned hb = bfr(h2v);
            const unsigned lb = bfr(h2v - __uint_as_float(hb << 16));
            const unsigned packed = (hb << 16) | lb;
            const unsigned nbp = (unsigned)__shfl_xor((int)packed, 1, 64);
            if ((jj & 1) == 0) {
                const unsigned hip = (packed >> 16) | (nbp & 0xffff0000u);
                const unsigned lop = (packed & 0xffffu) | (nbp << 16);
                const int k2 = s * 4 + (jj >> 1);
                ast64(EX2 + (size_t)(wr2 * Cn + c) * K2n * Bn + k2 * Bn + gb,
                      (u64)hip | ((u64)lop << 32));
            }

            float pv = h2v * wl;                      // partial of out over this slice's 8 h
            pv += __shfl_xor(pv, 1, 64);
            pv += __shfl_xor(pv, 2, 64);
            pv += __shfl_xor(pv, 4, 64);
            if (jj == 0) {
                if (use_part) {
                    part[(((t - 1) * Cn + c) * SLC + s) * Bn + gb] = pv;
                } else {
                    atomicAdd(&out[(gb * Tn + (t - 1)) * Cn + c], pv + (s == 0 ? bl : 0.0f));
                }
            }
        }

        // ---- per-(channel, batch-half) barrier: 32 slice-flags, independent pipeline ----
        __syncthreads();
        if (tid == 0)
            ast(&myflags[s * 64], (unsigned)(t + 1));
        if (tid < 64) {
            bool mine;
            do {
                mine = (tid >= SLC) ||
                       (ald(&myflags[tid * 64]) >= (unsigned)(t + 1));
                if (__all((int)mine)) break;
                __builtin_amdgcn_s_sleep(1);
            } while (true);
        }
        __syncthreads();
    }
}

__global__ void reduce_out(const float* __restrict__ part, const float* __restrict__ blin,
                           float* __restrict__ out) {
    const int t = blockIdx.x;           // 512
    const int c = threadIdx.x >> 5;     // 8
    const int b = threadIdx.x & 31;     // 32
    float v = blin[c];
#pragma unroll
    for (int s = 0; s < SLC; ++s) v += part[((t * Cn + c) * SLC + s) * Bn + b];
    out[(b * Tn + t) * Cn + c] = v;
}

extern "C" void kernel_launch(void* const* d_in, const int* in_sizes, int n_in,
                              void* d_out, int out_size, void* d_ws, size_t ws_size,
                              hipStream_t stream) {
    const float* x    = (const float*)d_in[0];
    const float* Wih1 = (const float*)d_in[1];
    const float* Whh1 = (const float*)d_in[2];
    const float* bih1 = (const float*)d_in[3];
    const float* bhh1 = (const float*)d_in[4];
    const float* Wih2 = (const float*)d_in[5];
    const float* Whh2 = (const float*)d_in[6];
    const float* bih2 = (const float*)d_in[7];
    const float* bhh2 = (const float*)d_in[8];
    const float* Wlin = (const float*)d_in[9];
    const float* blin = (const float*)d_in[10];
    float* out = (float*)d_out;

    const size_t h_bytes    = (size_t)2 * EXU * sizeof(u64);                // 1 MiB
    const size_t flag_bytes = (size_t)Cn * 2 * SLC * 64 * sizeof(unsigned); // 128 KiB
    const size_t part_bytes = (size_t)Tn * Cn * SLC * Bn * sizeof(float);   // 16 MiB
    const int use_part = (ws_size >= h_bytes + flag_bytes + part_bytes) ? 1 : 0;

    hipMemsetAsync(d_ws, 0, h_bytes + flag_bytes, stream);   // zero h state + flags
    if (!use_part)
        hipMemsetAsync(d_out, 0, (size_t)out_size * sizeof(float), stream);

    lstm_mfma<<<NBLK, NTHR, 0, stream>>>(
        x, Wih1, Whh1, bih1, bhh1, Wih2, Whh2, bih2, bhh2, Wlin, blin, out, d_ws, use_part);

    if (use_part) {
        const float* part = (const float*)((const char*)d_ws + h_bytes + flag_bytes);
        reduce_out<<<Tn, Cn * Bn, 0, stream>>>(part, blin, out);
    }
}